// Round 6
// baseline (946.374 us; speedup 1.0000x reference)
//
#include <hip/hip_runtime.h>
#include <hip/hip_fp16.h>
#include <math.h>

// Problem constants (match reference)
#define BB 8
#define SS 2048
#define TT 2048
#define ITERS 20
#define NEG_EPS_INV -10.0f     // -1/EPSILON
#define ROWS 32                // rows per block (4 chunks x 2 rows/wave x 4 waves)
#define NCHUNK 4
#define NTILE (SS / ROWS)      // 64 tiles
#define TINYF 1.17549435e-38f

typedef float vfloat4 __attribute__((ext_vector_type(4)));  // clang vector for nontemporal builtin

__device__ __forceinline__ float4 fma4v(float a, float4 x, float4 y) {
    return make_float4(fmaf(a, x.x, y.x), fmaf(a, x.y, y.y),
                       fmaf(a, x.z, y.z), fmaf(a, x.w, y.w));
}
__device__ __forceinline__ float4 max4(float4 a, float4 b) {
    return make_float4(fmaxf(a.x, b.x), fmaxf(a.y, b.y),
                       fmaxf(a.z, b.z), fmaxf(a.w, b.w));
}
__device__ __forceinline__ float hmax4(float4 a) {
    return fmaxf(fmaxf(a.x, a.y), fmaxf(a.z, a.w));
}
__device__ __forceinline__ float hsum4(float4 a) {
    return (a.x + a.y) + (a.z + a.w);
}
__device__ __forceinline__ float4 exp4m(float4 x, float m) {
    return make_float4(__expf(x.x - m), __expf(x.y - m),
                       __expf(x.z - m), __expf(x.w - m));
}
__device__ __forceinline__ uint h2u(__half2 h) {
    union { __half2 h; uint u; } c; c.h = h; return c.u;
}
__device__ __forceinline__ __half2 u2h(uint u) {
    union { __half2 h; uint u; } c; c.u = u; return c.h;
}
__device__ __forceinline__ uint2 pack4(float4 f) {
    uint2 r;
    r.x = h2u(__float22half2_rn(make_float2(f.x, f.y)));
    r.y = h2u(__float22half2_rn(make_float2(f.z, f.w)));
    return r;
}
__device__ __forceinline__ float4 unpack4(uint2 u) {
    float2 a = __half22float2(u2h(u.x));
    float2 b = __half22float2(u2h(u.y));
    return make_float4(a.x, a.y, b.x, b.y);
}
__device__ __forceinline__ void nt_store4(float4 v, float* p) {
    vfloat4 x = {v.x, v.y, v.z, v.w};
    __builtin_nontemporal_store(x, reinterpret_cast<vfloat4*>(p));
}

__global__ __launch_bounds__(256) void init_logv(float* __restrict__ log_v) {
    log_v[blockIdx.x * 256 + threadIdx.x] = 0.0f;   // grid = BB*TT/256
}

// One fused Sinkhorn iteration. Block owns 32 rows x 2048 cols of cost[b],
// processed as 4 chunks of 8 rows (2 rows per wave per chunk; row LSE fully
// in-wave). Column partials accumulate in REGISTERS across chunks:
//   P[tile,t] = sum_r exp(x[r,t]-M_r) * (mu_r/ssum_r)
// so v_new = log_nu + v_old - log(sum_tiles P). FIRST variant reads fp32 cost
// and writes the fp16 cache; later iterations read fp16 (half the bytes).
template <bool FIRST>
__global__ __launch_bounds__(256, 3) void fused_pass(
        const float* __restrict__ cost, const uint2* __restrict__ c16r,
        uint2* __restrict__ c16w, const float* __restrict__ mu,
        const float* __restrict__ log_v, float* __restrict__ log_u,
        float* __restrict__ P) {
    int t = threadIdx.x;
    int w = t >> 6, l = t & 63;
    int tile = blockIdx.x, b = blockIdx.y;

    const float4* v4 = (const float4*)(log_v + (size_t)b * TT);
    float4 vv[8];
#pragma unroll
    for (int i = 0; i < 8; ++i) vv[i] = v4[i * 64 + l];

    float4 acc[8];
#pragma unroll
    for (int i = 0; i < 8; ++i) acc[i] = make_float4(0.f, 0.f, 0.f, 0.f);

#pragma unroll
    for (int c = 0; c < NCHUNK; ++c) {
        int r0 = tile * ROWS + c * 8 + w * 2;     // wave's first row this chunk
        size_t rowbase = (size_t)(b * SS + r0) * TT;

        float4 x0[8], x1[8];
        if constexpr (FIRST) {
            const float4* c4 = (const float4*)(cost + rowbase);
            uint2* cw = c16w + rowbase / 4;       // uint2 = 4 halves
#pragma unroll
            for (int i = 0; i < 8; ++i) x0[i] = c4[i * 64 + l];
#pragma unroll
            for (int i = 0; i < 8; ++i) x1[i] = c4[512 + i * 64 + l];
#pragma unroll
            for (int i = 0; i < 8; ++i) {
                cw[i * 64 + l] = pack4(x0[i]);
                cw[512 + i * 64 + l] = pack4(x1[i]);
            }
        } else {
            const uint2* cr = c16r + rowbase / 4;
#pragma unroll
            for (int i = 0; i < 8; ++i) x0[i] = unpack4(cr[i * 64 + l]);
#pragma unroll
            for (int i = 0; i < 8; ++i) x1[i] = unpack4(cr[512 + i * 64 + l]);
        }
#pragma unroll
        for (int i = 0; i < 8; ++i) {
            x0[i] = fma4v(NEG_EPS_INV, x0[i], vv[i]);
            x1[i] = fma4v(NEG_EPS_INV, x1[i], vv[i]);
        }

        // row max (in-wave butterfly)
        float4 a0 = x0[0], a1 = x1[0];
#pragma unroll
        for (int i = 1; i < 8; ++i) { a0 = max4(a0, x0[i]); a1 = max4(a1, x1[i]); }
        float m0 = hmax4(a0), m1 = hmax4(a1);
#pragma unroll
        for (int off = 1; off < 64; off <<= 1) {
            m0 = fmaxf(m0, __shfl_xor(m0, off));
            m1 = fmaxf(m1, __shfl_xor(m1, off));
        }

        // e = exp(x - M) in place; row sums
        float ps0 = 0.0f, ps1 = 0.0f;
#pragma unroll
        for (int i = 0; i < 8; ++i) {
            x0[i] = exp4m(x0[i], m0);
            x1[i] = exp4m(x1[i], m1);
            ps0 += hsum4(x0[i]);
            ps1 += hsum4(x1[i]);
        }
#pragma unroll
        for (int off = 1; off < 64; off <<= 1) {
            ps0 += __shfl_xor(ps0, off);
            ps1 += __shfl_xor(ps1, off);
        }

        // g = mu/ssum;  u = log(g) - M
        float g0 = mu[b * SS + r0] / ps0;
        float g1 = mu[b * SS + r0 + 1] / ps1;
        if (l == 0) {
            log_u[b * SS + r0]     = __logf(fmaxf(g0, TINYF)) - m0;
            log_u[b * SS + r0 + 1] = __logf(fmaxf(g1, TINYF)) - m1;
        }

        // accumulate column partial in registers
#pragma unroll
        for (int i = 0; i < 8; ++i) {
            acc[i].x = fmaf(g0, x0[i].x, fmaf(g1, x1[i].x, acc[i].x));
            acc[i].y = fmaf(g0, x0[i].y, fmaf(g1, x1[i].y, acc[i].y));
            acc[i].z = fmaf(g0, x0[i].z, fmaf(g1, x1[i].z, acc[i].z));
            acc[i].w = fmaf(g0, x0[i].w, fmaf(g1, x1[i].w, acc[i].w));
        }
    }

    // cross-wave sum via LDS -> one 2048-col plane per block
    __shared__ float4 lds[4][512];
#pragma unroll
    for (int i = 0; i < 8; ++i) lds[w][i * 64 + l] = acc[i];
    __syncthreads();

    float4* P4 = (float4*)P + (size_t)(tile * BB + b) * 512;
#pragma unroll
    for (int k = 0; k < 2; ++k) {
        int j = k * 256 + t;
        float4 s0 = lds[0][j], s1 = lds[1][j], s2 = lds[2][j], s3 = lds[3][j];
        float4 o;
        o.x = (s0.x + s1.x) + (s2.x + s3.x);
        o.y = (s0.y + s1.y) + (s2.y + s3.y);
        o.z = (s0.z + s1.z) + (s2.z + s3.z);
        o.w = (s0.w + s1.w) + (s2.w + s3.w);
        P4[j] = o;
    }
}

// log_v_new[b,t] = log_nu + v_old - log(sum_tiles P[tile,b,t])
__global__ __launch_bounds__(256) void combine_v(
        const float* __restrict__ P, const float* __restrict__ nu,
        float* __restrict__ log_v) {
    int t = threadIdx.x;
    int seg = t >> 6, ci = t & 63;
    int col = blockIdx.x * 64 + ci;     // grid.x = TT/64
    int b = blockIdx.y;

    float s = 0.0f;
#pragma unroll 4
    for (int k = 0; k < NTILE / 4; ++k) {
        int tile = seg * (NTILE / 4) + k;
        s += P[((size_t)tile * BB + b) * TT + col];
    }
    __shared__ float lds[4][64];
    lds[seg][ci] = s;
    __syncthreads();
    if (t < 64) {
        float tot = (lds[0][ci] + lds[1][ci]) + (lds[2][ci] + lds[3][ci]);
        int i = b * TT + col;
        log_v[i] = __logf(fmaxf(nu[i], TINYF)) + log_v[i] - __logf(fmaxf(tot, TINYF));
    }
}

// transport = exp(log_pi), log_pi = log_u + (-cost/eps) + log_v  (fp16 cost cache)
__global__ __launch_bounds__(256) void finalize(const uint2* __restrict__ c16,
                                                const float* __restrict__ log_u,
                                                const float* __restrict__ log_v,
                                                float* __restrict__ transport,
                                                float* __restrict__ log_pi) {
    int i = blockIdx.x * 256 + threadIdx.x;  // float4 index
    int flat = i * 4;
    int row = flat >> 11;                    // / T
    int t = flat & (TT - 1);
    int b = row >> 11;                       // / S

    float lu = log_u[row];
    float4 lv = *reinterpret_cast<const float4*>(log_v + (size_t)b * TT + t);
    float4 c = unpack4(c16[((size_t)row * TT + t) / 4]);

    float4 lp;
    lp.x = fmaf(NEG_EPS_INV, c.x, lu + lv.x);
    lp.y = fmaf(NEG_EPS_INV, c.y, lu + lv.y);
    lp.z = fmaf(NEG_EPS_INV, c.z, lu + lv.z);
    lp.w = fmaf(NEG_EPS_INV, c.w, lu + lv.w);

    float4 tr;
    tr.x = __expf(lp.x);
    tr.y = __expf(lp.y);
    tr.z = __expf(lp.z);
    tr.w = __expf(lp.w);

    nt_store4(tr, transport + (size_t)row * TT + t);
    nt_store4(lp, log_pi + (size_t)row * TT + t);
}

extern "C" void kernel_launch(void* const* d_in, const int* in_sizes, int n_in,
                              void* d_out, int out_size, void* d_ws, size_t ws_size,
                              hipStream_t stream) {
    const float* cost = (const float*)d_in[0];
    const float* mu = (const float*)d_in[1];
    const float* nu = (const float*)d_in[2];

    float* out = (float*)d_out;
    float* transport = out;
    float* log_pi = out + (size_t)BB * SS * TT;

    // Scratch layout in d_ws: vectors, P planes, fp16 cost cache.
    float* ws = (float*)d_ws;
    float* log_u = ws;                       // 16K floats
    float* log_v = ws + 16384;               // 16K floats
    float* P = ws + (1 << 20);               // 4 MB offset; NTILE*BB*TT fl = 4.2 MB
    uint2* c16 = (uint2*)(ws + (1 << 23));   // 32 MB offset; B*S*T halves = 67 MB

    hipLaunchKernelGGL(init_logv, dim3(BB * TT / 256), dim3(256), 0, stream, log_v);

    hipLaunchKernelGGL((fused_pass<true>), dim3(NTILE, BB), dim3(256), 0, stream,
                       cost, c16, c16, mu, log_v, log_u, P);
    hipLaunchKernelGGL(combine_v, dim3(TT / 64, BB), dim3(256), 0, stream,
                       P, nu, log_v);

    for (int it = 1; it < ITERS; ++it) {
        hipLaunchKernelGGL((fused_pass<false>), dim3(NTILE, BB), dim3(256), 0, stream,
                           cost, c16, c16, mu, log_v, log_u, P);
        hipLaunchKernelGGL(combine_v, dim3(TT / 64, BB), dim3(256), 0, stream,
                           P, nu, log_v);
    }

    hipLaunchKernelGGL(finalize, dim3(BB * SS * TT / 4 / 256), dim3(256), 0, stream,
                       c16, log_u, log_v, transport, log_pi);
}

// Round 7
// 509.141 us; speedup vs baseline: 1.8588x; 1.8588x over previous
//
#include <hip/hip_runtime.h>
#include <hip/hip_fp16.h>
#include <math.h>

// Problem constants (match reference)
#define BB 8
#define SS 2048
#define TT 2048
#define ITERS 20
#define NEG_EPS_INV -10.0f     // -1/EPSILON
#define ROWS 16                // rows per block (2 chunks x 2 rows/wave x 4 waves)
#define NCHUNK 2
#define NTILE (SS / ROWS)      // 128 tiles
#define TINYF 1.17549435e-38f

typedef float vfloat4 __attribute__((ext_vector_type(4)));

__device__ __forceinline__ float4 fma4v(float a, float4 x, float4 y) {
    return make_float4(fmaf(a, x.x, y.x), fmaf(a, x.y, y.y),
                       fmaf(a, x.z, y.z), fmaf(a, x.w, y.w));
}
__device__ __forceinline__ float4 max4(float4 a, float4 b) {
    return make_float4(fmaxf(a.x, b.x), fmaxf(a.y, b.y),
                       fmaxf(a.z, b.z), fmaxf(a.w, b.w));
}
__device__ __forceinline__ float hmax4(float4 a) {
    return fmaxf(fmaxf(a.x, a.y), fmaxf(a.z, a.w));
}
__device__ __forceinline__ float hsum4(float4 a) {
    return (a.x + a.y) + (a.z + a.w);
}
__device__ __forceinline__ float4 exp4m(float4 x, float m) {
    return make_float4(__expf(x.x - m), __expf(x.y - m),
                       __expf(x.z - m), __expf(x.w - m));
}
__device__ __forceinline__ uint h2u(__half2 h) {
    union { __half2 h; uint u; } c; c.h = h; return c.u;
}
__device__ __forceinline__ __half2 u2h(uint u) {
    union { __half2 h; uint u; } c; c.u = u; return c.h;
}
__device__ __forceinline__ uint2 pack4(float4 f) {
    uint2 r;
    r.x = h2u(__float22half2_rn(make_float2(f.x, f.y)));
    r.y = h2u(__float22half2_rn(make_float2(f.z, f.w)));
    return r;
}
__device__ __forceinline__ float4 unpack4(uint2 u) {
    float2 a = __half22float2(u2h(u.x));
    float2 b = __half22float2(u2h(u.y));
    return make_float4(a.x, a.y, b.x, b.y);
}
__device__ __forceinline__ void nt_store4(float4 v, float* p) {
    vfloat4 x = {v.x, v.y, v.z, v.w};
    __builtin_nontemporal_store(x, reinterpret_cast<vfloat4*>(p));
}

__global__ __launch_bounds__(256) void init_logv(float* __restrict__ log_v) {
    log_v[blockIdx.x * 256 + threadIdx.x] = 0.0f;   // grid = BB*TT/256
}

// One fused Sinkhorn iteration. Block owns 16 rows x 2048 cols of cost[b],
// processed as 2 chunks of 8 rows (2 rows per wave per chunk; row LSE fully
// in-wave). Column partials accumulate in the wave's PRIVATE LDS plane across
// chunks (keeps register pressure at the proven no-spill level):
//   P[tile,t] = sum_r exp(x[r,t]-M_r) * (mu_r/ssum_r)
// v_new = log_nu + v_old - log(sum_tiles P). FIRST reads fp32 cost and writes
// the fp16 cache; later iterations read fp16 (half the bytes).
template <bool FIRST>
__global__ __launch_bounds__(256, 3) void fused_pass(
        const float* __restrict__ cost, const uint2* __restrict__ c16r,
        uint2* __restrict__ c16w, const float* __restrict__ mu,
        const float* __restrict__ log_v, float* __restrict__ log_u,
        float* __restrict__ P) {
    int t = threadIdx.x;
    int w = t >> 6, l = t & 63;
    int tile = blockIdx.x, b = blockIdx.y;

    __shared__ float4 lds[4][512];

    const float4* v4 = (const float4*)(log_v + (size_t)b * TT);
    float4 vv[8];
#pragma unroll
    for (int i = 0; i < 8; ++i) vv[i] = v4[i * 64 + l];

    // zero this wave's private accumulator plane (wave-private: no barrier)
#pragma unroll
    for (int i = 0; i < 8; ++i) lds[w][i * 64 + l] = make_float4(0.f, 0.f, 0.f, 0.f);

#pragma unroll
    for (int c = 0; c < NCHUNK; ++c) {
        int r0 = tile * ROWS + c * 8 + w * 2;     // wave's first row this chunk
        size_t rowbase = (size_t)(b * SS + r0) * TT;

        float4 x0[8], x1[8];
        if constexpr (FIRST) {
            const float4* c4 = (const float4*)(cost + rowbase);
            uint2* cw = c16w + rowbase / 4;       // uint2 = 4 halves
#pragma unroll
            for (int i = 0; i < 8; ++i) x0[i] = c4[i * 64 + l];
#pragma unroll
            for (int i = 0; i < 8; ++i) x1[i] = c4[512 + i * 64 + l];
#pragma unroll
            for (int i = 0; i < 8; ++i) {
                cw[i * 64 + l] = pack4(x0[i]);
                cw[512 + i * 64 + l] = pack4(x1[i]);
            }
        } else {
            const uint2* cr = c16r + rowbase / 4;
#pragma unroll
            for (int i = 0; i < 8; ++i) x0[i] = unpack4(cr[i * 64 + l]);
#pragma unroll
            for (int i = 0; i < 8; ++i) x1[i] = unpack4(cr[512 + i * 64 + l]);
        }
#pragma unroll
        for (int i = 0; i < 8; ++i) {
            x0[i] = fma4v(NEG_EPS_INV, x0[i], vv[i]);
            x1[i] = fma4v(NEG_EPS_INV, x1[i], vv[i]);
        }

        // row max (in-wave butterfly)
        float4 a0 = x0[0], a1 = x1[0];
#pragma unroll
        for (int i = 1; i < 8; ++i) { a0 = max4(a0, x0[i]); a1 = max4(a1, x1[i]); }
        float m0 = hmax4(a0), m1 = hmax4(a1);
#pragma unroll
        for (int off = 1; off < 64; off <<= 1) {
            m0 = fmaxf(m0, __shfl_xor(m0, off));
            m1 = fmaxf(m1, __shfl_xor(m1, off));
        }

        // e = exp(x - M) in place; row sums
        float ps0 = 0.0f, ps1 = 0.0f;
#pragma unroll
        for (int i = 0; i < 8; ++i) {
            x0[i] = exp4m(x0[i], m0);
            x1[i] = exp4m(x1[i], m1);
            ps0 += hsum4(x0[i]);
            ps1 += hsum4(x1[i]);
        }
#pragma unroll
        for (int off = 1; off < 64; off <<= 1) {
            ps0 += __shfl_xor(ps0, off);
            ps1 += __shfl_xor(ps1, off);
        }

        // g = mu/ssum;  u = log(g) - M
        float g0 = mu[b * SS + r0] / ps0;
        float g1 = mu[b * SS + r0 + 1] / ps1;
        if (l == 0) {
            log_u[b * SS + r0]     = __logf(fmaxf(g0, TINYF)) - m0;
            log_u[b * SS + r0 + 1] = __logf(fmaxf(g1, TINYF)) - m1;
        }

        // accumulate column partial into the wave's LDS plane
#pragma unroll
        for (int i = 0; i < 8; ++i) {
            float4 o = lds[w][i * 64 + l];
            o.x = fmaf(g0, x0[i].x, fmaf(g1, x1[i].x, o.x));
            o.y = fmaf(g0, x0[i].y, fmaf(g1, x1[i].y, o.y));
            o.z = fmaf(g0, x0[i].z, fmaf(g1, x1[i].z, o.z));
            o.w = fmaf(g0, x0[i].w, fmaf(g1, x1[i].w, o.w));
            lds[w][i * 64 + l] = o;
        }
    }
    __syncthreads();

    // cross-wave sum -> one 2048-col plane per block
    float4* P4 = (float4*)P + (size_t)(tile * BB + b) * 512;
#pragma unroll
    for (int k = 0; k < 2; ++k) {
        int j = k * 256 + t;
        float4 s0 = lds[0][j], s1 = lds[1][j], s2 = lds[2][j], s3 = lds[3][j];
        float4 o;
        o.x = (s0.x + s1.x) + (s2.x + s3.x);
        o.y = (s0.y + s1.y) + (s2.y + s3.y);
        o.z = (s0.z + s1.z) + (s2.z + s3.z);
        o.w = (s0.w + s1.w) + (s2.w + s3.w);
        P4[j] = o;
    }
}

// log_v_new[b,t] = log_nu + v_old - log(sum_tiles P[tile,b,t])
__global__ __launch_bounds__(256) void combine_v(
        const float* __restrict__ P, const float* __restrict__ nu,
        float* __restrict__ log_v) {
    int t = threadIdx.x;
    int seg = t >> 6, ci = t & 63;
    int col = blockIdx.x * 64 + ci;     // grid.x = TT/64
    int b = blockIdx.y;

    float s = 0.0f;
#pragma unroll 8
    for (int k = 0; k < NTILE / 4; ++k) {
        int tile = seg * (NTILE / 4) + k;
        s += P[((size_t)tile * BB + b) * TT + col];
    }
    __shared__ float lds[4][64];
    lds[seg][ci] = s;
    __syncthreads();
    if (t < 64) {
        float tot = (lds[0][ci] + lds[1][ci]) + (lds[2][ci] + lds[3][ci]);
        int i = b * TT + col;
        log_v[i] = __logf(fmaxf(nu[i], TINYF)) + log_v[i] - __logf(fmaxf(tot, TINYF));
    }
}

// transport = exp(log_pi), log_pi = log_u + (-cost/eps) + log_v  (fp16 cost cache)
__global__ __launch_bounds__(256) void finalize(const uint2* __restrict__ c16,
                                                const float* __restrict__ log_u,
                                                const float* __restrict__ log_v,
                                                float* __restrict__ transport,
                                                float* __restrict__ log_pi) {
    int i = blockIdx.x * 256 + threadIdx.x;  // float4 index
    int flat = i * 4;
    int row = flat >> 11;                    // / T
    int t = flat & (TT - 1);
    int b = row >> 11;                       // / S

    float lu = log_u[row];
    float4 lv = *reinterpret_cast<const float4*>(log_v + (size_t)b * TT + t);
    float4 c = unpack4(c16[((size_t)row * TT + t) / 4]);

    float4 lp;
    lp.x = fmaf(NEG_EPS_INV, c.x, lu + lv.x);
    lp.y = fmaf(NEG_EPS_INV, c.y, lu + lv.y);
    lp.z = fmaf(NEG_EPS_INV, c.z, lu + lv.z);
    lp.w = fmaf(NEG_EPS_INV, c.w, lu + lv.w);

    float4 tr;
    tr.x = __expf(lp.x);
    tr.y = __expf(lp.y);
    tr.z = __expf(lp.z);
    tr.w = __expf(lp.w);

    nt_store4(tr, transport + (size_t)row * TT + t);
    nt_store4(lp, log_pi + (size_t)row * TT + t);
}

extern "C" void kernel_launch(void* const* d_in, const int* in_sizes, int n_in,
                              void* d_out, int out_size, void* d_ws, size_t ws_size,
                              hipStream_t stream) {
    const float* cost = (const float*)d_in[0];
    const float* mu = (const float*)d_in[1];
    const float* nu = (const float*)d_in[2];

    float* out = (float*)d_out;
    float* transport = out;
    float* log_pi = out + (size_t)BB * SS * TT;

    // Scratch layout in d_ws: vectors, P planes, fp16 cost cache.
    float* ws = (float*)d_ws;
    float* log_u = ws;                       // 16K floats
    float* log_v = ws + 16384;               // 16K floats
    float* P = ws + (1 << 20);               // 4 MB offset; NTILE*BB*TT fl = 8.4 MB
    uint2* c16 = (uint2*)(ws + (1 << 23));   // 32 MB offset; B*S*T halves = 67 MB

    hipLaunchKernelGGL(init_logv, dim3(BB * TT / 256), dim3(256), 0, stream, log_v);

    hipLaunchKernelGGL((fused_pass<true>), dim3(NTILE, BB), dim3(256), 0, stream,
                       cost, c16, c16, mu, log_v, log_u, P);
    hipLaunchKernelGGL(combine_v, dim3(TT / 64, BB), dim3(256), 0, stream,
                       P, nu, log_v);

    for (int it = 1; it < ITERS; ++it) {
        hipLaunchKernelGGL((fused_pass<false>), dim3(NTILE, BB), dim3(256), 0, stream,
                           cost, c16, c16, mu, log_v, log_u, P);
        hipLaunchKernelGGL(combine_v, dim3(TT / 64, BB), dim3(256), 0, stream,
                           P, nu, log_v);
    }

    hipLaunchKernelGGL(finalize, dim3(BB * SS * TT / 4 / 256), dim3(256), 0, stream,
                       c16, log_u, log_v, transport, log_pi);
}